// Round 8
// baseline (451.200 us; speedup 1.0000x reference)
//
#include <hip/hip_runtime.h>

#define NCODES 1024
#define DIM 64
#define HW 4096       // 64*64
#define CHW 262144    // 64*4096
#define NPOS 131072   // 32*64*64
#define NELEM 8388608 // 32*64*64*64
#define TAU 4e-5f

// ws layout (bytes):
//  [0..4)            float loss accumulator (atomic)
//  [4..8)            uint ambiguous-count (atomic)
//  [256..4352)       int flags[1024]
//  [8192..270336)    ushort bswz[131072*2]  swizzled split-bf16 codebook frags
//  [270336..274432)  float cbnorm[1024]     (round-6-identical fmaf chain)
//  [274432..798720)  uint list[131072]      ambiguous position list
#define WS_LOSS 0
#define WS_CNT 4
#define WS_FLAGS 256
#define WS_BSWZ 8192
#define WS_CBN 270336
#define WS_LIST 274432
#define WS_NEEDED 798720

typedef __attribute__((ext_vector_type(8))) short bf16x8;
typedef __attribute__((ext_vector_type(4))) float f32x4;
typedef __attribute__((ext_vector_type(4))) unsigned int u32x4;

__device__ __forceinline__ unsigned short f2bf(float x) {  // RNE
  unsigned u = __float_as_uint(x);
  return (unsigned short)((u + 0x7FFFu + ((u >> 16) & 1u)) >> 16);
}
__device__ __forceinline__ float bf2f(unsigned short h) {
  return __uint_as_float(((unsigned)h) << 16);
}
// monotone float->uint order map and inverse
__device__ __forceinline__ unsigned fxf(float d) {
  unsigned u = __float_as_uint(d);
  return (u & 0x80000000u) ? ~u : (u | 0x80000000u);
}
__device__ __forceinline__ float fxi(unsigned u) {
  unsigned v = (u & 0x80000000u) ? (u ^ 0x80000000u) : ~u;
  return __uint_as_float(v);
}

// Prep: split codebook to bf16 hi/lo in MFMA-B-fragment order + exact cbnorm.
// Slot map (same formula used for A build in phase A -> k-map errors cancel):
//   frag unit addr (16B) = ((i*2+p)*2+q)*64 + l ; short e in [0,8)
//   n = i*16 + (l&15) ; k = q*32 + ((e>>2)<<4) + (((l>>4)&3)<<2) + (e&3)
__global__ __launch_bounds__(256) void vq_prep(const float* __restrict__ cb,
                                               unsigned short* __restrict__ bswz,
                                               float* __restrict__ cbn) {
  int t = blockIdx.x * 256 + threadIdx.x;  // 65536 threads = (n,k)
  int n = t >> 6, k = t & 63;
  float v = cb[n * 64 + k];
  unsigned short h = f2bf(v);
  unsigned short lo = f2bf(v - bf2f(h));
  int i = n >> 4, lmod = n & 15;
  int q = k >> 5, kr = k & 31;
  int e = ((kr >> 4) << 2) | (kr & 3);
  int l = lmod | (((kr >> 2) & 3) << 4);
  bswz[(((i * 2 + 0) * 2 + q) * 64 + l) * 8 + e] = h;
  bswz[(((i * 2 + 1) * 2 + q) * 64 + l) * 8 + e] = lo;
  if (k == 0) {  // cbnorm: bit-identical to round-6 cb_norms chain
    const float* ep = cb + n * 64;
    float s = 0.f;
#pragma unroll
    for (int c = 0; c < 64; ++c) s = fmaf(ep[c], ep[c], s);
    cbn[n] = s;
  }
}

// Phase A: 512 blocks x 512 threads; block owns 256 positions; wave owns 32.
__global__ __launch_bounds__(512, 4) void vq_phaseA(
    const float* __restrict__ z, const float* __restrict__ cb,
    const unsigned short* __restrict__ bswz, const float* __restrict__ cbn,
    float* __restrict__ out_zq, float* __restrict__ out_idx,
    float* __restrict__ loss, unsigned* __restrict__ cnt,
    unsigned* __restrict__ list, int* __restrict__ flags) {
  const int tid = threadIdx.x, w = tid >> 6, l = tid & 63;
  const int l15 = l & 15, lg = (l >> 4) & 3;
  const int posbase = blockIdx.x * 256;
  const int b = posbase >> 12;        // uniform per block (256 | 4096)
  const int hwb = posbase & 4095;

  // Build A-frags (z rows) in registers: 2 strips x 2 K-chunks x {hi,lo}
  bf16x8 A[2][2][2];
#pragma unroll
  for (int s = 0; s < 2; ++s) {
    const float* zp = z + (size_t)b * CHW + (hwb + w * 32 + s * 16 + l15);
#pragma unroll
    for (int q = 0; q < 2; ++q) {
      bf16x8 ah, al;
#pragma unroll
      for (int e = 0; e < 8; ++e) {
        int c = q * 32 + ((e >> 2) << 4) + (lg << 2) + (e & 3);
        float v = zp[c * HW];
        unsigned short h = f2bf(v);
        ah[e] = (short)h;
        al[e] = (short)f2bf(v - bf2f(h));
      }
      A[s][q][0] = ah;
      A[s][q][1] = al;
    }
  }

  unsigned long long mk[2][4];  // packed (xform(dist)<<32)|idx running min
  unsigned m2[2][4];            // second-best dist (xform space)
#pragma unroll
  for (int s = 0; s < 2; ++s)
#pragma unroll
    for (int r = 0; r < 4; ++r) { mk[s][r] = ~0ull; m2[s][r] = 0xFFFFFFFFu; }

  const u32x4* B = (const u32x4*)bswz;
  for (int i = 0; i < 64; ++i) {  // 16 codes per iter
    bf16x8 b00 = __builtin_bit_cast(bf16x8, B[(i * 4 + 0) * 64 + l]);  // hi q0
    bf16x8 b01 = __builtin_bit_cast(bf16x8, B[(i * 4 + 1) * 64 + l]);  // hi q1
    bf16x8 b10 = __builtin_bit_cast(bf16x8, B[(i * 4 + 2) * 64 + l]);  // lo q0
    bf16x8 b11 = __builtin_bit_cast(bf16x8, B[(i * 4 + 3) * 64 + l]);  // lo q1
    float cbnv = cbn[i * 16 + l15];
    unsigned nb = (unsigned)(i * 16 + l15);
#pragma unroll
    for (int s = 0; s < 2; ++s) {
      f32x4 C = {0.f, 0.f, 0.f, 0.f};
      C = __builtin_amdgcn_mfma_f32_16x16x32_bf16(A[s][0][0], b00, C, 0, 0, 0);
      C = __builtin_amdgcn_mfma_f32_16x16x32_bf16(A[s][1][0], b01, C, 0, 0, 0);
      C = __builtin_amdgcn_mfma_f32_16x16x32_bf16(A[s][0][0], b10, C, 0, 0, 0);
      C = __builtin_amdgcn_mfma_f32_16x16x32_bf16(A[s][1][0], b11, C, 0, 0, 0);
      C = __builtin_amdgcn_mfma_f32_16x16x32_bf16(A[s][0][1], b00, C, 0, 0, 0);
      C = __builtin_amdgcn_mfma_f32_16x16x32_bf16(A[s][1][1], b01, C, 0, 0, 0);
#pragma unroll
      for (int r = 0; r < 4; ++r) {
        float d = fmaf(C[r], -2.0f, cbnv);  // ||e||^2 - 2 z.e (pos-const dropped)
        unsigned u = fxf(d);
        unsigned long long key = ((unsigned long long)u << 32) | nb;
        bool lt = key < mk[s][r];
        unsigned loser = lt ? (unsigned)(mk[s][r] >> 32) : u;
        if (lt) mk[s][r] = key;
        m2[s][r] = min(m2[s][r], loser);
      }
    }
  }

  // reduce over the 16 n-lanes (xor within low 4 lane bits)
#pragma unroll
  for (int s = 0; s < 2; ++s)
#pragma unroll
    for (int r = 0; r < 4; ++r) {
      unsigned long long k = mk[s][r];
      unsigned mm2 = m2[s][r];
#pragma unroll
      for (int st = 1; st < 16; st <<= 1) {
        unsigned long long ok = __shfl_xor(k, st, 64);
        unsigned o2 = __shfl_xor(mm2, st, 64);
        unsigned loser = (unsigned)((k < ok ? ok : k) >> 32);
        k = k < ok ? k : ok;
        mm2 = min(min(mm2, o2), loser);
      }
      mk[s][r] = k;
      m2[s][r] = mm2;
    }

  __shared__ unsigned res[256];
  if (l15 == 0) {
#pragma unroll
    for (int s = 0; s < 2; ++s)
#pragma unroll
      for (int r = 0; r < 4; ++r) {
        unsigned u1 = (unsigned)(mk[s][r] >> 32);
        float gap = fxi(m2[s][r]) - fxi(u1);
        unsigned bj = (unsigned)(mk[s][r] & 0xFFFFFFFFull);
        res[w * 32 + s * 16 + lg * 4 + r] = bj | ((gap <= TAU) ? 0x80000000u : 0u);
      }
  }
  __syncthreads();

  // epilogue: 512 threads over 256 positions, 32 channels per half
  const int pl = tid & 255, half = tid >> 8;
  unsigned pk = res[pl];
  unsigned bj = pk & 1023u;
  int pos = posbase + pl;
  float lsum = 0.f;
  if (pk & 0x80000000u) {
    if (half == 0) {
      unsigned idx = atomicAdd(cnt, 1u);
      list[idx] = (unsigned)pos;
    }
  } else {
    if (half == 0) {
      out_idx[pos] = (float)bj;
      flags[bj] = 1;
    }
    const float* zp = z + (size_t)b * CHW + (pos & 4095);
    const float* eb = cb + bj * 64;
    float* op = out_zq + (size_t)b * CHW + (pos & 4095);
#pragma unroll
    for (int cc = 0; cc < 32; ++cc) {
      int c = half * 32 + cc;
      float zv = zp[c * HW];
      float e = eb[c];
      float diff = e - zv;
      lsum = fmaf(diff, diff, lsum);
      op[c * HW] = zv + diff;  // z + (z_q - z): reference rounding
    }
  }
  for (int off = 32; off; off >>= 1) lsum += __shfl_down(lsum, off, 64);
  __shared__ float wsum[8];
  if (l == 0) wsum[w] = lsum;
  __syncthreads();
  if (tid == 0) {
    float t2 = 0.f;
#pragma unroll
    for (int i2 = 0; i2 < 8; ++i2) t2 += wsum[i2];
    atomicAdd(loss, t2);
  }
}

// Phase B: exact round-6 formula for ambiguous positions (1 pos per thread).
__global__ __launch_bounds__(256) void vq_phaseB(
    const float* __restrict__ z, const float* __restrict__ cb,
    const float* __restrict__ cbn, float* __restrict__ out_zq,
    float* __restrict__ out_idx, float* __restrict__ loss,
    const unsigned* __restrict__ cnt, const unsigned* __restrict__ list,
    int* __restrict__ flags) {
  unsigned total = *cnt;
  for (unsigned i = blockIdx.x * 256 + threadIdx.x; i < total;
       i += gridDim.x * 256) {
    int pos = (int)list[i];
    int b = pos >> 12, hw = pos & 4095;
    const float* zp = z + (size_t)b * CHW + hw;
    float zr[64];
#pragma unroll
    for (int c = 0; c < 64; ++c) zr[c] = zp[c * HW];
    float A = 0.f;
#pragma unroll
    for (int c = 0; c < 64; ++c) A = fmaf(zr[c], zr[c], A);
    float best = 3.4e38f;
    int bestj = 0;
    for (int j = 0; j < NCODES; ++j) {
      const float* ej = cb + j * 64;  // wave-uniform -> scalar loads
      float d0 = 0.f, d1 = 0.f, d2 = 0.f, d3 = 0.f;
#pragma unroll
      for (int k = 0; k < 64; k += 4) {
        d0 = fmaf(zr[k + 0], ej[k + 0], d0);
        d1 = fmaf(zr[k + 1], ej[k + 1], d1);
        d2 = fmaf(zr[k + 2], ej[k + 2], d2);
        d3 = fmaf(zr[k + 3], ej[k + 3], d3);
      }
      float dot = (d0 + d1) + (d2 + d3);
      float dist = (A + cbn[j]) - 2.0f * dot;
      if (dist < best) { best = dist; bestj = j; }
    }
    const float* eb = cb + bestj * 64;
    float* op = out_zq + (size_t)b * CHW + hw;
    float lsum = 0.f;
#pragma unroll
    for (int c = 0; c < 64; ++c) {
      float e = eb[c];
      float diff = e - zr[c];
      lsum = fmaf(diff, diff, lsum);
      op[c * HW] = zr[c] + diff;
    }
    out_idx[pos] = (float)bestj;
    flags[bestj] = 1;
    atomicAdd(loss, lsum);
  }
}

__global__ __launch_bounds__(1024) void vq_finalize(
    const int* __restrict__ flags, const float* __restrict__ loss,
    float* __restrict__ out_scalars) {
  __shared__ int cnt_[16];
  int t = threadIdx.x;
  int f = flags[t];
  for (int off = 32; off; off >>= 1) f += __shfl_down(f, off, 64);
  int lane = t & 63, wid = t >> 6;
  if (lane == 0) cnt_[wid] = f;
  __syncthreads();
  if (t == 0) {
    int c = 0;
#pragma unroll
    for (int i = 0; i < 16; ++i) c += cnt_[i];
    out_scalars[0] = 1.25f * (*loss) / (float)NELEM;  // vq_loss
    out_scalars[1] = (float)c / (float)NCODES;        // usage
  }
}

// ---- Fallback path (verified round-6 kernel) in case ws_size < WS_NEEDED ----
template <int W>
__device__ __forceinline__ void epilogue16(const float* __restrict__ eb,
                                           const float zr[DIM],
                                           float* __restrict__ op,
                                           float& lsum) {
#pragma unroll
  for (int cc = 0; cc < 16; ++cc) {
    const int c = W * 16 + cc;
    float e = eb[c];
    float diff = e - zr[c];
    lsum = fmaf(diff, diff, lsum);
    op[c * HW] = zr[c] + diff;
  }
}

__global__ __launch_bounds__(256, 2) void vq_main_fb(
    const float* __restrict__ z, const float* __restrict__ cb,
    const float* __restrict__ cbn, float* __restrict__ out_zq,
    float* __restrict__ out_idx, float* __restrict__ sum_ws,
    int* __restrict__ flags) {
  const int w = threadIdx.x >> 6;
  const int lane = threadIdx.x & 63;
  const int n = blockIdx.x * 64 + lane;
  const int b = n >> 12;
  const int hw = n & 4095;
  const float* zp = z + b * CHW + hw;
  float zr[DIM];
#pragma unroll
  for (int c = 0; c < DIM; ++c) zr[c] = zp[c * HW];
  float A = 0.f;
#pragma unroll
  for (int c = 0; c < DIM; ++c) A = fmaf(zr[c], zr[c], A);
  const int j0 = __builtin_amdgcn_readfirstlane(w * 256);
  float best = 3.4e38f;
  int bestj = j0;
  for (int jj = 0; jj < 256; ++jj) {
    const int j = j0 + jj;
    const float* ej = cb + j * DIM;
    float d0 = 0.f, d1 = 0.f, d2 = 0.f, d3 = 0.f;
#pragma unroll
    for (int k = 0; k < DIM; k += 4) {
      d0 = fmaf(zr[k + 0], ej[k + 0], d0);
      d1 = fmaf(zr[k + 1], ej[k + 1], d1);
      d2 = fmaf(zr[k + 2], ej[k + 2], d2);
      d3 = fmaf(zr[k + 3], ej[k + 3], d3);
    }
    float dot = (d0 + d1) + (d2 + d3);
    float dist = (A + cbn[j]) - 2.0f * dot;
    if (dist < best) { best = dist; bestj = j; }
  }
  __shared__ unsigned long long keys[4][64];
  unsigned long long mykey =
      ((unsigned long long)__float_as_uint(best) << 32) | (unsigned)bestj;
  keys[w][lane] = mykey;
  __syncthreads();
  unsigned long long k0 = keys[0][lane], k1 = keys[1][lane];
  unsigned long long k2 = keys[2][lane], k3 = keys[3][lane];
  unsigned long long ka = k0 < k1 ? k0 : k1;
  unsigned long long kb = k2 < k3 ? k2 : k3;
  unsigned long long kmin = ka < kb ? ka : kb;
  const int bj = (int)(kmin & 0xFFFFFFFFull);
  const float* eb = cb + bj * DIM;
  float* op = out_zq + b * CHW + hw;
  float lsum = 0.f;
  if (w == 0)      epilogue16<0>(eb, zr, op, lsum);
  else if (w == 1) epilogue16<1>(eb, zr, op, lsum);
  else if (w == 2) epilogue16<2>(eb, zr, op, lsum);
  else             epilogue16<3>(eb, zr, op, lsum);
  if (w == 0) {
    out_idx[n] = (float)bj;
    flags[bj] = 1;
  }
  for (int off = 32; off; off >>= 1) lsum += __shfl_down(lsum, off, 64);
  __shared__ float wsum[4];
  if (lane == 0) wsum[w] = lsum;
  __syncthreads();
  if (threadIdx.x == 0)
    atomicAdd(sum_ws, wsum[0] + wsum[1] + wsum[2] + wsum[3]);
}

__global__ __launch_bounds__(256) void cb_norms_fb(
    const float* __restrict__ cb, float* __restrict__ cbn) {
  int j = blockIdx.x * 256 + threadIdx.x;
  if (j < NCODES) {
    const float* e = cb + j * DIM;
    float s = 0.f;
#pragma unroll
    for (int k = 0; k < DIM; ++k) s = fmaf(e[k], e[k], s);
    cbn[j] = s;
  }
}

extern "C" void kernel_launch(void* const* d_in, const int* in_sizes, int n_in,
                              void* d_out, int out_size, void* d_ws, size_t ws_size,
                              hipStream_t stream) {
  const float* z = (const float*)d_in[0];
  const float* cb = (const float*)d_in[1];
  float* out = (float*)d_out;

  char* ws = (char*)d_ws;
  float* loss = (float*)(ws + WS_LOSS);
  unsigned* cnt = (unsigned*)(ws + WS_CNT);
  int* flags = (int*)(ws + WS_FLAGS);

  if (ws_size >= WS_NEEDED) {
    unsigned short* bswz = (unsigned short*)(ws + WS_BSWZ);
    float* cbn = (float*)(ws + WS_CBN);
    unsigned* list = (unsigned*)(ws + WS_LIST);
    hipMemsetAsync(d_ws, 0, 8192, stream);  // loss + cnt + flags
    vq_prep<<<256, 256, 0, stream>>>(cb, bswz, cbn);
    vq_phaseA<<<512, 512, 0, stream>>>(z, cb, bswz, cbn, out, out + NELEM + 2,
                                       loss, cnt, list, flags);
    vq_phaseB<<<64, 256, 0, stream>>>(z, cb, cbn, out, out + NELEM + 2, loss,
                                      cnt, list, flags);
    vq_finalize<<<1, NCODES, 0, stream>>>(flags, loss, out + NELEM);
  } else {
    float* cbn = (float*)(ws + 4352);
    hipMemsetAsync(d_ws, 0, 4352, stream);
    cb_norms_fb<<<4, 256, 0, stream>>>(cb, cbn);
    vq_main_fb<<<NPOS / 64, 256, 0, stream>>>(z, cb, cbn, out, out + NELEM + 2,
                                              loss, flags);
    vq_finalize<<<1, NCODES, 0, stream>>>(flags, loss, out + NELEM);
  }
}

// Round 9
// 257.552 us; speedup vs baseline: 1.7519x; 1.7519x over previous
//
#include <hip/hip_runtime.h>

#define NCODES 1024
#define DIM 64
#define HW 4096       // 64*64
#define CHW 262144    // 64*4096
#define NPOS 131072   // 32*64*64
#define NELEM 8388608 // 32*64*64*64
#define TAU 4e-5f

// ws layout (bytes):
//  [0..4)            float loss accumulator (atomic)
//  [4..8)            uint ambiguous-count (atomic)
//  [256..4352)       int flags[1024]
//  [8192..270336)    ushort bswz[131072*2]  swizzled split-bf16 codebook frags
//  [270336..274432)  float cbnorm[1024]     (round-6-identical fmaf chain)
//  [274432..798720)  uint list[131072]      ambiguous position list
#define WS_LOSS 0
#define WS_CNT 4
#define WS_FLAGS 256
#define WS_BSWZ 8192
#define WS_CBN 270336
#define WS_LIST 274432

typedef __attribute__((ext_vector_type(8))) short bf16x8;
typedef __attribute__((ext_vector_type(4))) float f32x4;
typedef __attribute__((ext_vector_type(4))) unsigned int u32x4;

__device__ __forceinline__ unsigned short f2bf(float x) {  // RNE
  unsigned u = __float_as_uint(x);
  return (unsigned short)((u + 0x7FFFu + ((u >> 16) & 1u)) >> 16);
}
__device__ __forceinline__ float bf2f(unsigned short h) {
  return __uint_as_float(((unsigned)h) << 16);
}
// monotone float->uint order map and inverse
__device__ __forceinline__ unsigned fxf(float d) {
  unsigned u = __float_as_uint(d);
  return (u & 0x80000000u) ? ~u : (u | 0x80000000u);
}
__device__ __forceinline__ float fxi(unsigned u) {
  unsigned v = (u & 0x80000000u) ? (u ^ 0x80000000u) : ~u;
  return __uint_as_float(v);
}

// Prep: split codebook to bf16 hi/lo in MFMA-B-fragment order + exact cbnorm.
__global__ __launch_bounds__(256) void vq_prep(const float* __restrict__ cb,
                                               unsigned short* __restrict__ bswz,
                                               float* __restrict__ cbn) {
  int t = blockIdx.x * 256 + threadIdx.x;  // 65536 threads = (n,k)
  int n = t >> 6, k = t & 63;
  float v = cb[n * 64 + k];
  unsigned short h = f2bf(v);
  unsigned short lo = f2bf(v - bf2f(h));
  int i = n >> 4, lmod = n & 15;
  int q = k >> 5, kr = k & 31;
  int e = ((kr >> 4) << 2) | (kr & 3);
  int l = lmod | (((kr >> 2) & 3) << 4);
  bswz[(((i * 2 + 0) * 2 + q) * 64 + l) * 8 + e] = h;
  bswz[(((i * 2 + 1) * 2 + q) * 64 + l) * 8 + e] = lo;
  if (k == 0) {  // cbnorm: bit-identical to round-6 cb_norms chain
    const float* ep = cb + n * 64;
    float s = 0.f;
#pragma unroll
    for (int c = 0; c < 64; ++c) s = fmaf(ep[c], ep[c], s);
    cbn[n] = s;
  }
}

// Phase A: 512 blocks x 512 threads; block owns 256 positions; wave owns 32.
__global__ __launch_bounds__(512, 4) void vq_phaseA(
    const float* __restrict__ z, const float* __restrict__ cb,
    const unsigned short* __restrict__ bswz, const float* __restrict__ cbn,
    float* __restrict__ out_zq, float* __restrict__ out_idx,
    float* __restrict__ loss, unsigned* __restrict__ cnt,
    unsigned* __restrict__ list, int* __restrict__ flags) {
  const int tid = threadIdx.x, w = tid >> 6, l = tid & 63;
  const int l15 = l & 15, lg = (l >> 4) & 3;
  const int posbase = blockIdx.x * 256;
  const int b = posbase >> 12;        // uniform per block (256 | 4096)
  const int hwb = posbase & 4095;

  // Build A-frags (z rows) in registers: 2 strips x 2 K-chunks x {hi,lo}
  bf16x8 A[2][2][2];
#pragma unroll
  for (int s = 0; s < 2; ++s) {
    const float* zp = z + (size_t)b * CHW + (hwb + w * 32 + s * 16 + l15);
#pragma unroll
    for (int q = 0; q < 2; ++q) {
      bf16x8 ah, al;
#pragma unroll
      for (int e = 0; e < 8; ++e) {
        int c = q * 32 + ((e >> 2) << 4) + (lg << 2) + (e & 3);
        float v = zp[c * HW];
        unsigned short h = f2bf(v);
        ah[e] = (short)h;
        al[e] = (short)f2bf(v - bf2f(h));
      }
      A[s][q][0] = ah;
      A[s][q][1] = al;
    }
  }

  unsigned long long mk[2][4];  // packed (xform(dist)<<32)|idx running min
  unsigned m2[2][4];            // second-best dist (xform space)
#pragma unroll
  for (int s = 0; s < 2; ++s)
#pragma unroll
    for (int r = 0; r < 4; ++r) { mk[s][r] = ~0ull; m2[s][r] = 0xFFFFFFFFu; }

  const u32x4* B = (const u32x4*)bswz;
  for (int i = 0; i < 64; ++i) {  // 16 codes per iter
    bf16x8 b00 = __builtin_bit_cast(bf16x8, B[(i * 4 + 0) * 64 + l]);  // hi q0
    bf16x8 b01 = __builtin_bit_cast(bf16x8, B[(i * 4 + 1) * 64 + l]);  // hi q1
    bf16x8 b10 = __builtin_bit_cast(bf16x8, B[(i * 4 + 2) * 64 + l]);  // lo q0
    bf16x8 b11 = __builtin_bit_cast(bf16x8, B[(i * 4 + 3) * 64 + l]);  // lo q1
    float cbnv = cbn[i * 16 + l15];
    unsigned nb = (unsigned)(i * 16 + l15);
#pragma unroll
    for (int s = 0; s < 2; ++s) {
      f32x4 C = {0.f, 0.f, 0.f, 0.f};
      C = __builtin_amdgcn_mfma_f32_16x16x32_bf16(A[s][0][0], b00, C, 0, 0, 0);
      C = __builtin_amdgcn_mfma_f32_16x16x32_bf16(A[s][1][0], b01, C, 0, 0, 0);
      C = __builtin_amdgcn_mfma_f32_16x16x32_bf16(A[s][0][0], b10, C, 0, 0, 0);
      C = __builtin_amdgcn_mfma_f32_16x16x32_bf16(A[s][1][0], b11, C, 0, 0, 0);
      C = __builtin_amdgcn_mfma_f32_16x16x32_bf16(A[s][0][1], b00, C, 0, 0, 0);
      C = __builtin_amdgcn_mfma_f32_16x16x32_bf16(A[s][1][1], b01, C, 0, 0, 0);
#pragma unroll
      for (int r = 0; r < 4; ++r) {
        float d = fmaf(C[r], -2.0f, cbnv);  // ||e||^2 - 2 z.e (pos-const dropped)
        unsigned u = fxf(d);
        unsigned long long key = ((unsigned long long)u << 32) | nb;
        bool lt = key < mk[s][r];
        unsigned loser = lt ? (unsigned)(mk[s][r] >> 32) : u;
        if (lt) mk[s][r] = key;
        m2[s][r] = min(m2[s][r], loser);
      }
    }
  }

  // reduce over the 16 n-lanes (xor within low 4 lane bits)
#pragma unroll
  for (int s = 0; s < 2; ++s)
#pragma unroll
    for (int r = 0; r < 4; ++r) {
      unsigned long long k = mk[s][r];
      unsigned mm2 = m2[s][r];
#pragma unroll
      for (int st = 1; st < 16; st <<= 1) {
        unsigned long long ok = __shfl_xor(k, st, 64);
        unsigned o2 = __shfl_xor(mm2, st, 64);
        unsigned loser = (unsigned)((k < ok ? ok : k) >> 32);
        k = k < ok ? k : ok;
        mm2 = min(min(mm2, o2), loser);
      }
      mk[s][r] = k;
      m2[s][r] = mm2;
    }

  __shared__ unsigned res[256];
  if (l15 == 0) {
#pragma unroll
    for (int s = 0; s < 2; ++s)
#pragma unroll
      for (int r = 0; r < 4; ++r) {
        unsigned u1 = (unsigned)(mk[s][r] >> 32);
        float gap = fxi(m2[s][r]) - fxi(u1);
        unsigned bj = (unsigned)(mk[s][r] & 0xFFFFFFFFull);
        res[w * 32 + s * 16 + lg * 4 + r] = bj | ((gap <= TAU) ? 0x80000000u : 0u);
      }
  }
  __syncthreads();

  // epilogue: 512 threads over 256 positions, 32 channels per half
  const int pl = tid & 255, half = tid >> 8;
  unsigned pk = res[pl];
  unsigned bj = pk & 1023u;
  int pos = posbase + pl;
  float lsum = 0.f;
  if (pk & 0x80000000u) {
    if (half == 0) {
      unsigned idx = atomicAdd(cnt, 1u);
      list[idx] = (unsigned)pos;
    }
  } else {
    if (half == 0) {
      out_idx[pos] = (float)bj;
      flags[bj] = 1;
    }
    const float* zp = z + (size_t)b * CHW + (pos & 4095);
    const float* eb = cb + bj * 64;
    float* op = out_zq + (size_t)b * CHW + (pos & 4095);
#pragma unroll
    for (int cc = 0; cc < 32; ++cc) {
      int c = half * 32 + cc;
      float zv = zp[c * HW];
      float e = eb[c];
      float diff = e - zv;
      lsum = fmaf(diff, diff, lsum);
      op[c * HW] = zv + diff;  // z + (z_q - z): reference rounding
    }
  }
  for (int off = 32; off; off >>= 1) lsum += __shfl_down(lsum, off, 64);
  __shared__ float wsum[8];
  if (l == 0) wsum[w] = lsum;
  __syncthreads();
  if (tid == 0) {
    float t2 = 0.f;
#pragma unroll
    for (int i2 = 0; i2 < 8; ++i2) t2 += wsum[i2];
    atomicAdd(loss, t2);
  }
}

// Phase B: one BLOCK per ambiguous position (round-8 fix: was 1 thread/pos,
// 382us of serial issue latency at 0.4% occupancy). Each thread computes the
// exact round-6 FMA chain for 4 codes; per-code dist values are bit-identical
// to the serial scan, and packed u64-min (lowest index wins ties) reproduces
// the sequential first-min tie-break exactly.
__global__ __launch_bounds__(256) void vq_phaseB(
    const float* __restrict__ z, const float* __restrict__ cb,
    const float* __restrict__ cbn, float* __restrict__ out_zq,
    float* __restrict__ out_idx, float* __restrict__ loss,
    const unsigned* __restrict__ cnt, const unsigned* __restrict__ list,
    int* __restrict__ flags) {
  const unsigned total = *cnt;
  const int t = threadIdx.x;
  const int l = t & 63, w = t >> 6;
  __shared__ float zsh[64];
  __shared__ unsigned long long wred[4];
  __shared__ unsigned bjsh;

  for (unsigned i = blockIdx.x; i < total; i += gridDim.x) {
    const int pos = (int)list[i];
    const int b = pos >> 12, hw = pos & 4095;
    const float* zp = z + (size_t)b * CHW + hw;
    __syncthreads();  // protect zsh/wred reuse across loop iterations
    if (t < 64) zsh[t] = zp[t * HW];
    __syncthreads();

    // ||z||^2: identical fmaf chain as the serial formula
    float A = 0.f;
#pragma unroll
    for (int c = 0; c < 64; ++c) A = fmaf(zsh[c], zsh[c], A);

    unsigned long long best = ~0ull;
#pragma unroll
    for (int jj = 0; jj < 4; ++jj) {
      const int j = jj * 256 + t;
      const float* ej = cb + j * 64;
      float d0 = 0.f, d1 = 0.f, d2 = 0.f, d3 = 0.f;
#pragma unroll
      for (int k = 0; k < 64; k += 4) {
        d0 = fmaf(zsh[k + 0], ej[k + 0], d0);
        d1 = fmaf(zsh[k + 1], ej[k + 1], d1);
        d2 = fmaf(zsh[k + 2], ej[k + 2], d2);
        d3 = fmaf(zsh[k + 3], ej[k + 3], d3);
      }
      float dot = (d0 + d1) + (d2 + d3);
      float dist = (A + cbn[j]) - 2.0f * dot;
      unsigned long long key =
          ((unsigned long long)fxf(dist) << 32) | (unsigned)j;
      best = best < key ? best : key;
    }

    // reduce 256 keys: wave butterfly then cross-wave via LDS
    for (int st = 1; st < 64; st <<= 1) {
      unsigned long long ok = __shfl_xor(best, st, 64);
      best = best < ok ? best : ok;
    }
    if (l == 0) wred[w] = best;
    __syncthreads();
    if (t == 0) {
      unsigned long long ka = wred[0] < wred[1] ? wred[0] : wred[1];
      unsigned long long kb = wred[2] < wred[3] ? wred[2] : wred[3];
      unsigned long long km = ka < kb ? ka : kb;
      unsigned bj = (unsigned)(km & 0xFFFFFFFFull);
      bjsh = bj;
      out_idx[pos] = (float)bj;
      flags[bj] = 1;
    }
    __syncthreads();
    const unsigned bj = bjsh;

    // epilogue: threads 0..63 write one channel each
    float lsum = 0.f;
    if (t < 64) {
      float zv = zsh[t];
      float e = cb[bj * 64 + t];
      float diff = e - zv;
      lsum = fmaf(diff, diff, 0.f);
      out_zq[(size_t)b * CHW + (size_t)t * HW + hw] = zv + diff;
      for (int off = 32; off; off >>= 1) lsum += __shfl_down(lsum, off, 64);
      if (t == 0) atomicAdd(loss, lsum);
    }
  }
}

__global__ __launch_bounds__(1024) void vq_finalize(
    const int* __restrict__ flags, const float* __restrict__ loss,
    float* __restrict__ out_scalars) {
  __shared__ int cnt_[16];
  int t = threadIdx.x;
  int f = flags[t];
  for (int off = 32; off; off >>= 1) f += __shfl_down(f, off, 64);
  int lane = t & 63, wid = t >> 6;
  if (lane == 0) cnt_[wid] = f;
  __syncthreads();
  if (t == 0) {
    int c = 0;
#pragma unroll
    for (int i = 0; i < 16; ++i) c += cnt_[i];
    out_scalars[0] = 1.25f * (*loss) / (float)NELEM;  // vq_loss
    out_scalars[1] = (float)c / (float)NCODES;        // usage
  }
}

extern "C" void kernel_launch(void* const* d_in, const int* in_sizes, int n_in,
                              void* d_out, int out_size, void* d_ws, size_t ws_size,
                              hipStream_t stream) {
  const float* z = (const float*)d_in[0];
  const float* cb = (const float*)d_in[1];
  float* out = (float*)d_out;

  char* ws = (char*)d_ws;
  float* loss = (float*)(ws + WS_LOSS);
  unsigned* cnt = (unsigned*)(ws + WS_CNT);
  int* flags = (int*)(ws + WS_FLAGS);
  unsigned short* bswz = (unsigned short*)(ws + WS_BSWZ);
  float* cbn = (float*)(ws + WS_CBN);
  unsigned* list = (unsigned*)(ws + WS_LIST);

  hipMemsetAsync(d_ws, 0, 8192, stream);  // loss + cnt + flags
  vq_prep<<<256, 256, 0, stream>>>(cb, bswz, cbn);
  vq_phaseA<<<512, 512, 0, stream>>>(z, cb, bswz, cbn, out, out + NELEM + 2,
                                     loss, cnt, list, flags);
  vq_phaseB<<<2048, 256, 0, stream>>>(z, cb, cbn, out, out + NELEM + 2, loss,
                                      cnt, list, flags);
  vq_finalize<<<1, NCODES, 0, stream>>>(flags, loss, out + NELEM);
}

// Round 10
// 219.068 us; speedup vs baseline: 2.0596x; 1.1757x over previous
//
#include <hip/hip_runtime.h>

#define NCODES 1024
#define DIM 64
#define HW 4096       // 64*64
#define CHW 262144    // 64*4096
#define NPOS 131072   // 32*64*64
#define NELEM 8388608 // 32*64*64*64
#define TAU 4e-5f

// ws layout (bytes):
//  [0..4)            float loss accumulator (atomic)
//  [4..8)            uint ambiguous-count (atomic)
//  [256..4352)       int flags[1024]
//  [8192..270336)    ushort bswz[131072*2]  swizzled split-bf16 codebook frags
//  [270336..274432)  float cbnorm[1024]     (round-6-identical fmaf chain)
//  [274432..798720)  uint list[131072]      ambiguous position list
#define WS_LOSS 0
#define WS_CNT 4
#define WS_FLAGS 256
#define WS_BSWZ 8192
#define WS_CBN 270336
#define WS_LIST 274432

typedef __attribute__((ext_vector_type(8))) short bf16x8;
typedef __attribute__((ext_vector_type(4))) float f32x4;
typedef __attribute__((ext_vector_type(4))) unsigned int u32x4;

__device__ __forceinline__ unsigned short f2bf(float x) {  // RNE
  unsigned u = __float_as_uint(x);
  return (unsigned short)((u + 0x7FFFu + ((u >> 16) & 1u)) >> 16);
}
__device__ __forceinline__ float bf2f(unsigned short h) {
  return __uint_as_float(((unsigned)h) << 16);
}
// monotone float->uint order map (for u64 key packing in phase B)
__device__ __forceinline__ unsigned fxf(float d) {
  unsigned u = __float_as_uint(d);
  return (u & 0x80000000u) ? ~u : (u | 0x80000000u);
}

// Prep: split codebook to bf16 hi/lo in MFMA-B-fragment order + exact cbnorm.
__global__ __launch_bounds__(256) void vq_prep(const float* __restrict__ cb,
                                               unsigned short* __restrict__ bswz,
                                               float* __restrict__ cbn) {
  int t = blockIdx.x * 256 + threadIdx.x;  // 65536 threads = (n,k)
  int n = t >> 6, k = t & 63;
  float v = cb[n * 64 + k];
  unsigned short h = f2bf(v);
  unsigned short lo = f2bf(v - bf2f(h));
  int i = n >> 4, lmod = n & 15;
  int q = k >> 5, kr = k & 31;
  int e = ((kr >> 4) << 2) | (kr & 3);
  int l = lmod | (((kr >> 2) & 3) << 4);
  bswz[(((i * 2 + 0) * 2 + q) * 64 + l) * 8 + e] = h;
  bswz[(((i * 2 + 1) * 2 + q) * 64 + l) * 8 + e] = lo;
  if (k == 0) {  // cbnorm: bit-identical to round-6 cb_norms chain
    const float* ep = cb + n * 64;
    float s = 0.f;
#pragma unroll
    for (int c = 0; c < 64; ++c) s = fmaf(ep[c], ep[c], s);
    cbn[n] = s;
  }
}

// Phase A: 512 blocks x 512 threads; block owns 256 positions; wave owns 32.
__global__ __launch_bounds__(512, 4) void vq_phaseA(
    const float* __restrict__ z, const float* __restrict__ cb,
    const unsigned short* __restrict__ bswz, const float* __restrict__ cbn,
    float* __restrict__ out_zq, float* __restrict__ out_idx,
    float* __restrict__ loss, unsigned* __restrict__ cnt,
    unsigned* __restrict__ list, int* __restrict__ flags) {
  const int tid = threadIdx.x, w = tid >> 6, l = tid & 63;
  const int l15 = l & 15, lg = (l >> 4) & 3;
  const int posbase = blockIdx.x * 256;
  const int b = posbase >> 12;        // uniform per block (256 | 4096)
  const int hwb = posbase & 4095;

  // Build A-frags (z rows) in registers: 2 strips x 2 K-chunks x {hi,lo}
  bf16x8 A[2][2][2];
#pragma unroll
  for (int s = 0; s < 2; ++s) {
    const float* zp = z + (size_t)b * CHW + (hwb + w * 32 + s * 16 + l15);
#pragma unroll
    for (int q = 0; q < 2; ++q) {
      bf16x8 ah, al;
#pragma unroll
      for (int e = 0; e < 8; ++e) {
        int c = q * 32 + ((e >> 2) << 4) + (lg << 2) + (e & 3);
        float v = zp[c * HW];
        unsigned short h = f2bf(v);
        ah[e] = (short)h;
        al[e] = (short)f2bf(v - bf2f(h));
      }
      A[s][q][0] = ah;
      A[s][q][1] = al;
    }
  }

  // float-based min / second-min / index tracking (round-10: 5 VALU/update
  // vs 8 for fxf-u64 packing; provably order-identical, strict < first-wins)
  float bd[2][4], b2[2][4];
  unsigned bi[2][4];
#pragma unroll
  for (int s = 0; s < 2; ++s)
#pragma unroll
    for (int r = 0; r < 4; ++r) {
      bd[s][r] = 3.4e38f; b2[s][r] = 3.4e38f; bi[s][r] = 0;
    }

  const u32x4* B = (const u32x4*)bswz;
  for (int i = 0; i < 64; ++i) {  // 16 codes per iter
    bf16x8 b00 = __builtin_bit_cast(bf16x8, B[(i * 4 + 0) * 64 + l]);  // hi q0
    bf16x8 b01 = __builtin_bit_cast(bf16x8, B[(i * 4 + 1) * 64 + l]);  // hi q1
    bf16x8 b10 = __builtin_bit_cast(bf16x8, B[(i * 4 + 2) * 64 + l]);  // lo q0
    bf16x8 b11 = __builtin_bit_cast(bf16x8, B[(i * 4 + 3) * 64 + l]);  // lo q1
    float cbnv = cbn[i * 16 + l15];
    unsigned nb = (unsigned)(i * 16 + l15);
#pragma unroll
    for (int s = 0; s < 2; ++s) {
      f32x4 C = {0.f, 0.f, 0.f, 0.f};
      C = __builtin_amdgcn_mfma_f32_16x16x32_bf16(A[s][0][0], b00, C, 0, 0, 0);
      C = __builtin_amdgcn_mfma_f32_16x16x32_bf16(A[s][1][0], b01, C, 0, 0, 0);
      C = __builtin_amdgcn_mfma_f32_16x16x32_bf16(A[s][0][0], b10, C, 0, 0, 0);
      C = __builtin_amdgcn_mfma_f32_16x16x32_bf16(A[s][1][0], b11, C, 0, 0, 0);
      C = __builtin_amdgcn_mfma_f32_16x16x32_bf16(A[s][0][1], b00, C, 0, 0, 0);
      C = __builtin_amdgcn_mfma_f32_16x16x32_bf16(A[s][1][1], b01, C, 0, 0, 0);
#pragma unroll
      for (int r = 0; r < 4; ++r) {
        float d = fmaf(C[r], -2.0f, cbnv);  // ||e||^2 - 2 z.e (pos-const dropped)
        bool lt = d < bd[s][r];
        float loser = lt ? bd[s][r] : d;
        b2[s][r] = fminf(b2[s][r], loser);
        bd[s][r] = fminf(bd[s][r], d);
        bi[s][r] = lt ? nb : bi[s][r];
      }
    }
  }

  // reduce over the 16 n-lanes (xor within low 4 lane bits)
  __shared__ unsigned res[256];
#pragma unroll
  for (int s = 0; s < 2; ++s)
#pragma unroll
    for (int r = 0; r < 4; ++r) {
      float d = bd[s][r], s2 = b2[s][r];
      unsigned idx = bi[s][r];
#pragma unroll
      for (int st = 1; st < 16; st <<= 1) {
        float od = __shfl_xor(d, st, 64);
        unsigned oi = __shfl_xor(idx, st, 64);
        float o2 = __shfl_xor(s2, st, 64);
        bool take = (od < d) || (od == d && oi < idx);
        float loser = take ? d : od;
        s2 = fminf(fminf(s2, o2), loser);
        d = take ? od : d;
        idx = take ? oi : idx;
      }
      if (l15 == 0) {
        float gap = s2 - d;
        res[w * 32 + s * 16 + lg * 4 + r] =
            idx | ((gap <= TAU) ? 0x80000000u : 0u);
      }
    }
  __syncthreads();

  // epilogue: 512 threads over 256 positions, 32 channels per half
  const int pl = tid & 255, half = tid >> 8;
  unsigned pk = res[pl];
  unsigned bj = pk & 1023u;
  int pos = posbase + pl;
  float lsum = 0.f;
  if (pk & 0x80000000u) {
    if (half == 0) {
      unsigned idx = atomicAdd(cnt, 1u);
      list[idx] = (unsigned)pos;
    }
  } else {
    if (half == 0) {
      out_idx[pos] = (float)bj;
      flags[bj] = 1;
    }
    const float* zp = z + (size_t)b * CHW + (pos & 4095);
    const float* eb = cb + bj * 64;
    float* op = out_zq + (size_t)b * CHW + (pos & 4095);
#pragma unroll
    for (int cc = 0; cc < 32; ++cc) {
      int c = half * 32 + cc;
      float zv = zp[c * HW];
      float e = eb[c];
      float diff = e - zv;
      lsum = fmaf(diff, diff, lsum);
      op[c * HW] = zv + diff;  // z + (z_q - z): reference rounding
    }
  }
  for (int off = 32; off; off >>= 1) lsum += __shfl_down(lsum, off, 64);
  __shared__ float wsum[8];
  if (l == 0) wsum[w] = lsum;
  __syncthreads();
  if (tid == 0) {
    float t2 = 0.f;
#pragma unroll
    for (int i2 = 0; i2 < 8; ++i2) t2 += wsum[i2];
    atomicAdd(loss, t2);
  }
}

// Phase B v3 (round-10): round-6 structure over the compacted list.
// lane = list position (per-lane zr gather), wave = 128-code chunk on the
// wave-uniform scalar-load path. Identical per-code FMA chain as the serial
// formula; u64 (dist,idx) min reproduces the first-min tie-break exactly.
template <int W>
__device__ __forceinline__ void epilogue8(const float* __restrict__ eb,
                                          const float zr[DIM],
                                          float* __restrict__ op,
                                          float& lsum) {
#pragma unroll
  for (int cc = 0; cc < 8; ++cc) {
    const int c = W * 8 + cc;
    float e = eb[c];
    float diff = e - zr[c];
    lsum = fmaf(diff, diff, lsum);
    op[c * HW] = zr[c] + diff;
  }
}

__global__ __launch_bounds__(512, 2) void vq_phaseB(
    const float* __restrict__ z, const float* __restrict__ cb,
    const float* __restrict__ cbn, float* __restrict__ out_zq,
    float* __restrict__ out_idx, float* __restrict__ loss,
    const unsigned* __restrict__ cnt, const unsigned* __restrict__ list,
    int* __restrict__ flags) {
  const unsigned total = *cnt;
  const int t = threadIdx.x, w = t >> 6, l = t & 63;
  __shared__ unsigned long long keys[8][64];
  __shared__ float wsum[8];

  for (unsigned base = blockIdx.x * 64u; base < total; base += 2048u * 64u) {
    const bool active = (base + (unsigned)l) < total;
    const int pos = active ? (int)list[base + l] : 0;
    const int b = pos >> 12, hw = pos & 4095;
    const float* zp = z + (size_t)b * CHW + hw;

    float zr[DIM];
#pragma unroll
    for (int c = 0; c < DIM; ++c) zr[c] = zp[c * HW];
    float A = 0.f;
#pragma unroll
    for (int c = 0; c < DIM; ++c) A = fmaf(zr[c], zr[c], A);

    const int j0 = __builtin_amdgcn_readfirstlane(w * 128);
    float best = 3.4e38f;
    int bestj = j0;
    for (int jj = 0; jj < 128; ++jj) {
      const int j = j0 + jj;
      const float* ej = cb + j * 64;  // wave-uniform -> scalar loads
      float d0 = 0.f, d1 = 0.f, d2 = 0.f, d3 = 0.f;
#pragma unroll
      for (int k = 0; k < 64; k += 4) {
        d0 = fmaf(zr[k + 0], ej[k + 0], d0);
        d1 = fmaf(zr[k + 1], ej[k + 1], d1);
        d2 = fmaf(zr[k + 2], ej[k + 2], d2);
        d3 = fmaf(zr[k + 3], ej[k + 3], d3);
      }
      float dot = (d0 + d1) + (d2 + d3);
      float dist = (A + cbn[j]) - 2.0f * dot;
      if (dist < best) { best = dist; bestj = j; }
    }

    __syncthreads();  // protect keys/wsum reuse across grid-stride iters
    keys[w][l] = ((unsigned long long)fxf(best) << 32) | (unsigned)bestj;
    __syncthreads();
    unsigned long long km = keys[0][l];
#pragma unroll
    for (int ww = 1; ww < 8; ++ww) {
      unsigned long long k2 = keys[ww][l];
      km = km < k2 ? km : k2;
    }
    const unsigned bj = (unsigned)(km & 0xFFFFFFFFull);

    float lsum = 0.f;
    if (active) {
      const float* eb = cb + bj * 64;
      float* op = out_zq + (size_t)b * CHW + hw;
      if (w == 0)      epilogue8<0>(eb, zr, op, lsum);
      else if (w == 1) epilogue8<1>(eb, zr, op, lsum);
      else if (w == 2) epilogue8<2>(eb, zr, op, lsum);
      else if (w == 3) epilogue8<3>(eb, zr, op, lsum);
      else if (w == 4) epilogue8<4>(eb, zr, op, lsum);
      else if (w == 5) epilogue8<5>(eb, zr, op, lsum);
      else if (w == 6) epilogue8<6>(eb, zr, op, lsum);
      else             epilogue8<7>(eb, zr, op, lsum);
      if (w == 0) {
        out_idx[pos] = (float)bj;
        flags[bj] = 1;
      }
    }
    for (int off = 32; off; off >>= 1) lsum += __shfl_down(lsum, off, 64);
    if (l == 0) wsum[w] = lsum;
    __syncthreads();
    if (t == 0) {
      float t2 = 0.f;
#pragma unroll
      for (int i2 = 0; i2 < 8; ++i2) t2 += wsum[i2];
      atomicAdd(loss, t2);
    }
  }
}

__global__ __launch_bounds__(1024) void vq_finalize(
    const int* __restrict__ flags, const float* __restrict__ loss,
    float* __restrict__ out_scalars) {
  __shared__ int cnt_[16];
  int t = threadIdx.x;
  int f = flags[t];
  for (int off = 32; off; off >>= 1) f += __shfl_down(f, off, 64);
  int lane = t & 63, wid = t >> 6;
  if (lane == 0) cnt_[wid] = f;
  __syncthreads();
  if (t == 0) {
    int c = 0;
#pragma unroll
    for (int i = 0; i < 16; ++i) c += cnt_[i];
    out_scalars[0] = 1.25f * (*loss) / (float)NELEM;  // vq_loss
    out_scalars[1] = (float)c / (float)NCODES;        // usage
  }
}

extern "C" void kernel_launch(void* const* d_in, const int* in_sizes, int n_in,
                              void* d_out, int out_size, void* d_ws, size_t ws_size,
                              hipStream_t stream) {
  const float* z = (const float*)d_in[0];
  const float* cb = (const float*)d_in[1];
  float* out = (float*)d_out;

  char* ws = (char*)d_ws;
  float* loss = (float*)(ws + WS_LOSS);
  unsigned* cnt = (unsigned*)(ws + WS_CNT);
  int* flags = (int*)(ws + WS_FLAGS);
  unsigned short* bswz = (unsigned short*)(ws + WS_BSWZ);
  float* cbn = (float*)(ws + WS_CBN);
  unsigned* list = (unsigned*)(ws + WS_LIST);

  hipMemsetAsync(d_ws, 0, 8192, stream);  // loss + cnt + flags
  vq_prep<<<256, 256, 0, stream>>>(cb, bswz, cbn);
  vq_phaseA<<<512, 512, 0, stream>>>(z, cb, bswz, cbn, out, out + NELEM + 2,
                                     loss, cnt, list, flags);
  vq_phaseB<<<2048, 512, 0, stream>>>(z, cb, cbn, out, out + NELEM + 2, loss,
                                      cnt, list, flags);
  vq_finalize<<<1, NCODES, 0, stream>>>(flags, loss, out + NELEM);
}